// Round 2
// baseline (225.808 us; speedup 1.0000x reference)
//
#include <hip/hip_runtime.h>

// SSIM 3D loss: pred/target f32 [4,1,64,192,192], scalar 1 - mean(ssim_map).
// v12: FULL FUSION. One kernel per (16x16 HW tile, D-half, batch) streams
//      D-planes: stage 26x26 halo -> W-blur 5 fields (fp16 LDS, 6/px packed)
//      -> H-blur -> D-blur via 11-deep shifting register accumulators
//      (5 fields x 11 slots, compile-time indexed) -> online SSIM emit.
//      Kills the 94 MB intermediate write + re-read and kernel B entirely.
//      SP=48 (stage pitch): row stride = 16 banks mod 32 -> 2-way max (free).

#define D_DIM 64
#define H_DIM 192
#define W_DIM 192
#define SLICE (H_DIM * W_DIM)   // 36864
#define VOL   (D_DIM * SLICE)   // 2359296
#define NB    4
#define KS    11
#define RAD   5
#define TIL   16                // output tile 16x16
#define HLO   26                // halo extent
#define SP    48                // staging pitch (fp32): 16 banks/row -> 2-way
#define IPX   6                 // fp16 per px in interm (5 fields + pad)
#define C1F   (0.01f * 0.01f)
#define C2F   (0.03f * 0.03f)

typedef _Float16 h2v __attribute__((ext_vector_type(2)));

__device__ __forceinline__ void make_window(float* g) {
    float s = 0.f;
#pragma unroll
    for (int i = 0; i < KS; ++i) {
        float c = (float)(i - RAD);
        g[i] = expf(-(c * c) * (1.0f / 4.5f));  // 2*sigma^2 = 4.5
        s += g[i];
    }
    float inv = 1.0f / s;
#pragma unroll
    for (int i = 0; i < KS; ++i) g[i] *= inv;
}

#define SSIM_ACC(MP, MT, E2, T2, PT) do {                                 \
    float _mps = (MP) * (MP), _mts = (MT) * (MT), _mpt = (MP) * (MT);     \
    float _num = (2.f * _mpt + C1F) * (2.f * ((PT) - _mpt) + C2F);        \
    float _den = (_mps + _mts + C1F) *                                    \
                 (((E2) - _mps) + ((T2) - _mts) + C2F);                   \
    ssim_sum += _num * __builtin_amdgcn_rcpf(_den);                       \
} while (0)

__global__ __launch_bounds__(256) void fused_ssim_kernel(
    const float* __restrict__ pred, const float* __restrict__ targ,
    float* __restrict__ partials) {
    __shared__ float spb[HLO * SP];                  // 4992 B
    __shared__ float stb[HLO * SP];                  // 4992 B
    __shared__ __attribute__((aligned(16))) _Float16 interm[HLO * TIL * IPX]; // 4992 B
    __shared__ float red[4];

    float g[KS];
    make_window(g);

    const int tid = threadIdx.x;
    const int h0 = (blockIdx.x / 12) * TIL;
    const int w0 = (blockIdx.x % 12) * TIL;
    const int half = blockIdx.y;
    const float* pb = pred + (size_t)blockIdx.z * VOL;
    const float* tb = targ + (size_t)blockIdx.z * VOL;
    const int q0 = half ? 27 : 0;                    // first plane
    const int q1 = half ? 63 : 36;                   // last plane (incl)
    const int d_lo = half ? 32 : 0;
    const int d_hi = half ? 63 : 31;

    // ---- plane-invariant staging precompute (676 halo px, 3 strides) ----
    int sidx[3], slds[3];
    bool sa[3], sv[3];
#pragma unroll
    for (int k = 0; k < 3; ++k) {
        int i = tid + 256 * k;
        sa[k] = i < HLO * HLO;
        int y = i / HLO, x = i - y * HLO;
        int gh = h0 + y - RAD, gw = w0 + x - RAD;
        sv[k] = sa[k] && (unsigned)gh < (unsigned)H_DIM &&
                (unsigned)gw < (unsigned)W_DIM;
        sidx[k] = gh * W_DIM + gw;
        slds[k] = y * SP + x;
    }
    const int py = tid >> 4, px = tid & 15;          // H-phase pixel

    // ---- D-window accumulators: slot j = output d = q + j - 5 ----
    float a0[KS], a1[KS], a2[KS], a3[KS], a4[KS];
#pragma unroll
    for (int j = 0; j < KS; ++j)
        a0[j] = a1[j] = a2[j] = a3[j] = a4[j] = 0.f;
    float ssim_sum = 0.f;

    // prologue: load plane q0 into regs
    float rp[3], rt[3];
    {
        const float* pq = pb + q0 * SLICE;
        const float* tq = tb + q0 * SLICE;
#pragma unroll
        for (int k = 0; k < 3; ++k) {
            rp[k] = sv[k] ? pq[sidx[k]] : 0.f;
            rt[k] = sv[k] ? tq[sidx[k]] : 0.f;
        }
    }

    for (int q = q0;; ++q) {
        __syncthreads();                             // LDS free (prev phases done)
        // commit staged regs -> LDS
#pragma unroll
        for (int k = 0; k < 3; ++k)
            if (sa[k]) { spb[slds[k]] = rp[k]; stb[slds[k]] = rt[k]; }
        // prefetch next plane (latency hidden under this plane's compute)
        if (q < q1) {
            const float* pn = pb + (q + 1) * SLICE;
            const float* tn = tb + (q + 1) * SLICE;
#pragma unroll
            for (int k = 0; k < 3; ++k) {
                rp[k] = sv[k] ? pn[sidx[k]] : 0.f;
                rt[k] = sv[k] ? tn[sidx[k]] : 0.f;
            }
        }
        __syncthreads();                             // staging visible

        // ---- W phase: 416 tasks (26 rows x 16 cols), 5 derived fields ----
#pragma unroll
        for (int it = 0; it < 2; ++it) {
            int t = tid + it * 256;
            if (t < HLO * TIL) {
                int r = t >> 4, c = t & 15;
                const float* pr = spb + r * SP + c;
                const float* tr = stb + r * SP + c;
                float s0 = 0.f, s1 = 0.f, s2 = 0.f, s3 = 0.f, s4 = 0.f;
#pragma unroll
                for (int k = 0; k < KS; ++k) {
                    float pv = pr[k], tv = tr[k], gk = g[k];
                    s0 += gk * pv;
                    s1 += gk * tv;
                    s2 += gk * pv * pv;
                    s3 += gk * tv * tv;
                    s4 += gk * pv * tv;
                }
                _Float16* ip = interm + t * IPX;
                h2v w01, w23;
                w01[0] = (_Float16)s0; w01[1] = (_Float16)s1;
                w23[0] = (_Float16)s2; w23[1] = (_Float16)s3;
                *(h2v*)ip = w01;
                *(h2v*)(ip + 2) = w23;
                ip[4] = (_Float16)s4;
            }
        }
        __syncthreads();                             // interm visible

        // ---- H phase + D accumulate + emit ----
        {
            const _Float16* cb = interm + px * IPX;
            float v0 = 0.f, v1 = 0.f, v2 = 0.f, v3 = 0.f, v4 = 0.f;
#pragma unroll
            for (int k = 0; k < KS; ++k) {
                const _Float16* p = cb + (py + k) * (TIL * IPX);
                h2v w01 = *(const h2v*)p;
                h2v w23 = *(const h2v*)(p + 2);
                float gk = g[k];
                v0 += gk * (float)w01[0];
                v1 += gk * (float)w01[1];
                v2 += gk * (float)w23[0];
                v3 += gk * (float)w23[1];
                v4 += gk * (float)p[4];
            }
            // plane q contributes g[10-j] to output d = q + j - 5
#pragma unroll
            for (int j = 0; j < KS; ++j) {
                float wj = g[10 - j];
                a0[j] += wj * v0; a1[j] += wj * v1; a2[j] += wj * v2;
                a3[j] += wj * v3; a4[j] += wj * v4;
            }
            if (q - 5 >= d_lo)                       // d = q-5 complete; d<=d_hi holds
                SSIM_ACC(a0[0], a1[0], a2[0], a3[0], a4[0]);
            // shift window down (all compile-time indices -> registers)
#pragma unroll
            for (int j = 0; j < KS - 1; ++j) {
                a0[j] = a0[j + 1]; a1[j] = a1[j + 1]; a2[j] = a2[j + 1];
                a3[j] = a3[j + 1]; a4[j] = a4[j + 1];
            }
            a0[10] = 0.f; a1[10] = 0.f; a2[10] = 0.f; a3[10] = 0.f; a4[10] = 0.f;
        }
        if (q == q1) break;
    }

    // ---- tail: outputs d = q1-4 .. q1 (zero-padded D windows) ----
#pragma unroll
    for (int j = 0; j < 5; ++j) {
        int d = q1 - 4 + j;
        if (d >= d_lo && d <= d_hi)
            SSIM_ACC(a0[j], a1[j], a2[j], a3[j], a4[j]);
    }

    // ---- block reduction ----
    float a = ssim_sum;
#pragma unroll
    for (int off = 32; off > 0; off >>= 1) a += __shfl_down(a, off, 64);
    int lane = tid & 63, wv = tid >> 6;
    if (lane == 0) red[wv] = a;
    __syncthreads();
    if (tid == 0)
        partials[((blockIdx.z * 2 + blockIdx.y) * 144) + blockIdx.x] =
            red[0] + red[1] + red[2] + red[3];
}

// ---- final reduction ----
__global__ __launch_bounds__(256) void finalize_kernel(
    const float* __restrict__ partials, int n, float* __restrict__ out) {
    double a = 0.0;
    for (int i = threadIdx.x; i < n; i += 256) a += (double)partials[i];
#pragma unroll
    for (int off = 32; off > 0; off >>= 1) a += __shfl_down(a, off, 64);
    __shared__ double red[4];
    int lane = threadIdx.x & 63, wv = threadIdx.x >> 6;
    if (lane == 0) red[wv] = a;
    __syncthreads();
    if (threadIdx.x == 0) {
        double s = red[0] + red[1] + red[2] + red[3];
        out[0] = (float)(1.0 - s / (double)((long long)NB * VOL));
    }
}

extern "C" void kernel_launch(void* const* d_in, const int* in_sizes, int n_in,
                              void* d_out, int out_size, void* d_ws, size_t ws_size,
                              hipStream_t stream) {
    const float* pred = (const float*)d_in[0];
    const float* targ = (const float*)d_in[1];
    float* out = (float*)d_out;
    float* partials = (float*)d_ws;                  // NB*288 floats

    fused_ssim_kernel<<<dim3(144, 2, NB), 256, 0, stream>>>(pred, targ, partials);
    finalize_kernel<<<1, 256, 0, stream>>>(partials, NB * 288, out);
}